// Round 3
// baseline (7597.219 us; speedup 1.0000x reference)
//
#include <hip/hip_runtime.h>

// LightGCL forward: 2 layers of bipartite SpMM + mean of layer embeddings.
// Strategy: bucket the 10M (dest,src,val) entries into 256-row destination
// buckets (dense grouped writes), then accumulate each bucket in a 64KB LDS
// f32 accumulator (one block per bucket, zero float global atomics).
// Gather sources are bf16 (half the gather bandwidth).

constexpr int D = 64;
constexpr int RPB = 256;             // destination rows per bucket
constexpr int NBMAX = 2048;          // LDS histogram capacity
constexpr int PASSB_EDGES = 16384;   // edges per block in pass_bucket

static __device__ __forceinline__ unsigned short f32_to_bf16(float f) {
    unsigned u = __float_as_uint(f);
    unsigned r = u + 0x7FFFu + ((u >> 16) & 1u);
    return (unsigned short)(r >> 16);
}
static __device__ __forceinline__ float bf16_to_f32(unsigned short h) {
    return __uint_as_float(((unsigned)h) << 16);
}

// ---------------- bucket build ----------------

// Global per-bucket entry counts (LDS-aggregated).
__global__ void bucket_hist(const int* __restrict__ rows,
                            const int* __restrict__ cols,
                            int* __restrict__ bktCnt, int nu, int nnz, int NB) {
    __shared__ int cnt[NBMAX];
    for (int i = threadIdx.x; i < NB; i += blockDim.x) cnt[i] = 0;
    __syncthreads();
    int stride = gridDim.x * blockDim.x;
    for (int e = blockIdx.x * blockDim.x + threadIdx.x; e < nnz; e += stride) {
        atomicAdd(&cnt[rows[e] >> 8], 1);
        atomicAdd(&cnt[(nu + cols[e]) >> 8], 1);
    }
    __syncthreads();
    for (int i = threadIdx.x; i < NB; i += blockDim.x)
        if (cnt[i]) atomicAdd(&bktCnt[i], cnt[i]);
}

// Exclusive scan of bucket counts (single block). bktBase[NB] = total.
__global__ void scan_buckets(const int* __restrict__ bktCnt,
                             int* __restrict__ bktBase, int* __restrict__ bktCur,
                             int NB, int total) {
    __shared__ int tsum[256];
    int t = threadIdx.x;
    const int IT = (NB + 255) / 256;  // <= 8 for NB <= 2048
    int v[8];
    int s = 0;
    for (int k = 0; k < IT; k++) {
        int i = t * IT + k;
        v[k] = (i < NB) ? bktCnt[i] : 0;
        s += v[k];
    }
    tsum[t] = s;
    __syncthreads();
    for (int off = 1; off < 256; off <<= 1) {
        int x = (t >= off) ? tsum[t - off] : 0;
        __syncthreads();
        tsum[t] += x;
        __syncthreads();
    }
    int excl = (t > 0) ? tsum[t - 1] : 0;
    for (int k = 0; k < IT; k++) {
        int i = t * IT + k;
        if (i < NB) { bktBase[i] = excl; bktCur[i] = excl; excl += v[k]; }
    }
    if (t == 255) bktBase[NB] = total;
}

// Scatter entries grouped by bucket. Each block counts its per-bucket entries
// in LDS, reserves one contiguous chunk per bucket (1 atomic), then emits —
// so global writes are dense per (block,bucket) chunk.
// Entry pack: x = (rowlocal<<19) | src_global (src < 2^19), y = val bits.
__global__ __launch_bounds__(256) void pass_bucket(
    const float* __restrict__ vals, const int* __restrict__ rows,
    const int* __restrict__ cols, int* __restrict__ bktCur,
    int2* __restrict__ tmp, int nu, int nnz, int NB) {
    __shared__ int cnt[NBMAX];
    for (int i = threadIdx.x; i < NB; i += 256) cnt[i] = 0;
    __syncthreads();
    int base = blockIdx.x * PASSB_EDGES;
    for (int k = 0; k < PASSB_EDGES / 256; k++) {
        int e = base + k * 256 + threadIdx.x;
        if (e < nnz) {
            atomicAdd(&cnt[rows[e] >> 8], 1);
            atomicAdd(&cnt[(nu + cols[e]) >> 8], 1);
        }
    }
    __syncthreads();
    for (int i = threadIdx.x; i < NB; i += 256) {
        int c = cnt[i];
        if (c) cnt[i] = atomicAdd(&bktCur[i], c);  // chunk base -> LDS cursor
    }
    __syncthreads();
    for (int k = 0; k < PASSB_EDGES / 256; k++) {
        int e = base + k * 256 + threadIdx.x;
        if (e < nnz) {
            int r = rows[e], c = cols[e];
            int iv = __float_as_int(vals[e]);
            int gi = nu + c;
            int p1 = atomicAdd(&cnt[r >> 8], 1);
            tmp[p1] = make_int2(((r & 255) << 19) | gi, iv);
            int p2 = atomicAdd(&cnt[gi >> 8], 1);
            tmp[p2] = make_int2(((gi & 255) << 19) | r, iv);
        }
    }
}

// Concat + convert f32 embeddings -> bf16 table [nR][D].
__global__ void convert_e0(const float* __restrict__ Eu,
                           const float* __restrict__ Ei,
                           unsigned short* __restrict__ Ecat,
                           long long nuD, long long nD) {
    long long stride = (long long)gridDim.x * blockDim.x * 4;
    for (long long i = ((long long)blockIdx.x * blockDim.x + threadIdx.x) * 4;
         i < nD; i += stride) {
        const float* src = (i < nuD) ? (Eu + i) : (Ei + (i - nuD));
        float4 f = *(const float4*)src;
        unsigned short o0 = f32_to_bf16(f.x), o1 = f32_to_bf16(f.y);
        unsigned short o2 = f32_to_bf16(f.z), o3 = f32_to_bf16(f.w);
        unsigned v0 = ((unsigned)o1 << 16) | o0;
        unsigned v1 = ((unsigned)o3 << 16) | o2;
        *(uint2*)(Ecat + i) = make_uint2(v0, v1);
    }
}

// ---------------- bucket accumulate (the SpMM) ----------------
// One block per bucket; 64KB LDS f32 accumulator [256 rows][64 dims].
// Per entry: one 128B coalesced bf16 gather + 64 conflict-free ds_add_f32.
// FUSE=false: Zout_bf16[row] = sum           (layer 1)
// FUSE=true : out[row] = (E0 + Z1 + sum)/3   (layer 2 + combine)
template <bool FUSE>
__global__ __launch_bounds__(1024) void accum_kernel(
    const int2* __restrict__ tmp, const int* __restrict__ bktBase,
    const unsigned short* __restrict__ gsrc,  // bf16 [nR][D] gather source
    const float* __restrict__ Eu0, const float* __restrict__ Ei0,
    const unsigned short* __restrict__ Z1,
    unsigned short* __restrict__ Zout,
    float* __restrict__ out_u, float* __restrict__ out_i,
    int nu, int nR) {
    __shared__ float acc[RPB * D];  // 65536 bytes
    for (int i = threadIdx.x; i < RPB * D; i += 1024) acc[i] = 0.f;
    __syncthreads();

    int b = blockIdx.x;
    int beg = bktBase[b], end = bktBase[b + 1];
    int n = end - beg;
    int wid = threadIdx.x >> 6, lane = threadIdx.x & 63;
    int per = (n + 15) >> 4;  // 16 waves
    int s0 = beg + wid * per;
    int s1 = min(beg + (wid + 1) * per, end);
    for (int e = s0; e < s1; e++) {
        int2 s = tmp[e];
        int srcRow = s.x & 0x7FFFF;
        int rl = s.x >> 19;
        float v = __int_as_float(s.y);
        float g = bf16_to_f32(gsrc[(long long)srcRow * D + lane]);
        atomicAdd(&acc[rl * D + lane], v * g);
    }
    __syncthreads();

    // 1024 threads -> 256 rows x 4 chunks of 16 dims
    int rl = threadIdx.x >> 2;
    int d0 = (threadIdx.x & 3) * 16;
    int gr = (b << 8) + rl;
    if (gr >= nR) return;
    const float* ap = &acc[rl * D + d0];
    if (!FUSE) {
        unsigned short* dst = Zout + (long long)gr * D + d0;
#pragma unroll
        for (int j = 0; j < 16; j += 2) {
            unsigned a = f32_to_bf16(ap[j]);
            unsigned c = f32_to_bf16(ap[j + 1]);
            *(unsigned*)(dst + j) = (c << 16) | a;
        }
    } else {
        const float* e0 = (gr < nu) ? (Eu0 + (long long)gr * D + d0)
                                    : (Ei0 + (long long)(gr - nu) * D + d0);
        const unsigned short* z1 = Z1 + (long long)gr * D + d0;
        float* dst = (gr < nu) ? (out_u + (long long)gr * D + d0)
                               : (out_i + (long long)(gr - nu) * D + d0);
        const float inv3 = 1.f / 3.f;
#pragma unroll
        for (int j = 0; j < 16; j += 4) {
            float4 a = *(const float4*)(e0 + j);
            float4 o;
            o.x = (a.x + bf16_to_f32(z1[j + 0]) + ap[j + 0]) * inv3;
            o.y = (a.y + bf16_to_f32(z1[j + 1]) + ap[j + 1]) * inv3;
            o.z = (a.z + bf16_to_f32(z1[j + 2]) + ap[j + 2]) * inv3;
            o.w = (a.w + bf16_to_f32(z1[j + 3]) + ap[j + 3]) * inv3;
            *(float4*)(dst + j) = o;
        }
    }
}

// ---------------- fallback (atomic scatter, needs only 77 MB ws) ----------------

__global__ void spmm_edge(const float* __restrict__ vals,
                          const int* __restrict__ rows,
                          const int* __restrict__ cols,
                          const float* __restrict__ Eu,
                          const float* __restrict__ Ei,
                          float* __restrict__ Zu, float* __restrict__ Zi,
                          float scale, int nnz) {
    long long gid = (long long)blockIdx.x * blockDim.x + threadIdx.x;
    if (gid >= (long long)nnz * D) return;
    int e = (int)(gid >> 6);
    int d = (int)(gid & 63);
    float v = vals[e] * scale;
    long long r = rows[e];
    long long c = cols[e];
    atomicAdd(&Zu[r * D + d], v * Ei[c * D + d]);
    atomicAdd(&Zi[c * D + d], v * Eu[r * D + d]);
}

__global__ void combine_kernel(const float* __restrict__ E0,
                               const float* __restrict__ Z1,
                               float* __restrict__ out, long long n4) {
    long long i = (long long)blockIdx.x * blockDim.x + threadIdx.x;
    if (i >= n4) return;
    const float4 a = reinterpret_cast<const float4*>(E0)[i];
    const float4 b = reinterpret_cast<const float4*>(Z1)[i];
    const float inv3 = 1.0f / 3.0f;
    float4 o;
    o.x = (a.x + b.x) * inv3;
    o.y = (a.y + b.y) * inv3;
    o.z = (a.z + b.z) * inv3;
    o.w = (a.w + b.w) * inv3;
    reinterpret_cast<float4*>(out)[i] = o;
}

// ---------------- launcher ----------------

static inline size_t align256(size_t x) { return (x + 255) & ~(size_t)255; }

extern "C" void kernel_launch(void* const* d_in, const int* in_sizes, int n_in,
                              void* d_out, int out_size, void* d_ws, size_t ws_size,
                              hipStream_t stream) {
    const float* user_emb = (const float*)d_in[0];
    const float* item_emb = (const float*)d_in[1];
    const float* vals     = (const float*)d_in[2];
    const int*   rows     = (const int*)d_in[3];
    const int*   cols     = (const int*)d_in[4];

    const int nu  = in_sizes[0] / D;  // 100000
    const int ni  = in_sizes[1] / D;  // 200000
    const int nnz = in_sizes[2];      // 5000000
    const int nR  = nu + ni;
    const int NB  = (nR + RPB - 1) / RPB;  // 1172

    float* out_u = (float*)d_out;
    float* out_i = out_u + (size_t)nu * D;

    // ws layout
    size_t off = 0;
    size_t o_tmp  = off; off += align256((size_t)2 * nnz * sizeof(int2));
    size_t o_E    = off; off += align256((size_t)nR * D * sizeof(unsigned short));
    size_t o_Z1   = off; off += align256((size_t)nR * D * sizeof(unsigned short));
    size_t o_cnt  = off; off += align256((size_t)(NB + 1) * sizeof(int));
    size_t o_base = off; off += align256((size_t)(NB + 2) * sizeof(int));
    size_t o_cur  = off; off += align256((size_t)(NB + 1) * sizeof(int));
    size_t needed = off;

    bool fits19 = (nR < (1 << 19));  // src index must pack in 19 bits

    if (ws_size >= needed && NB <= NBMAX && fits19) {
        char* w = (char*)d_ws;
        int2*           tmp     = (int2*)(w + o_tmp);
        unsigned short* Ecat    = (unsigned short*)(w + o_E);
        unsigned short* Z1bf    = (unsigned short*)(w + o_Z1);
        int*            bktCnt  = (int*)(w + o_cnt);
        int*            bktBase = (int*)(w + o_base);
        int*            bktCur  = (int*)(w + o_cur);

        hipMemsetAsync(bktCnt, 0, (size_t)NB * sizeof(int), stream);

        bucket_hist<<<512, 256, 0, stream>>>(rows, cols, bktCnt, nu, nnz, NB);
        scan_buckets<<<1, 256, 0, stream>>>(bktCnt, bktBase, bktCur, NB, 2 * nnz);

        unsigned gB = (unsigned)((nnz + PASSB_EDGES - 1) / PASSB_EDGES);
        pass_bucket<<<gB, 256, 0, stream>>>(vals, rows, cols, bktCur, tmp,
                                            nu, nnz, NB);

        long long nD = (long long)nR * D;
        long long nuD = (long long)nu * D;
        unsigned gC = (unsigned)((nD / 4 + 255) / 256);
        if (gC > 4096) gC = 4096;
        convert_e0<<<gC, 256, 0, stream>>>(user_emb, item_emb, Ecat, nuD, nD);

        // Layer 1: Z1 = A_cat @ E0  (all 300k destination rows in one dispatch)
        accum_kernel<false><<<NB, 1024, 0, stream>>>(
            tmp, bktBase, Ecat, nullptr, nullptr, nullptr, Z1bf,
            nullptr, nullptr, nu, nR);
        // Layer 2 + combine: out = (E0 + Z1 + A_cat @ Z1) / 3
        accum_kernel<true><<<NB, 1024, 0, stream>>>(
            tmp, bktBase, Z1bf, user_emb, item_emb, Z1bf, nullptr,
            out_u, out_i, nu, nR);
    } else {
        // Fallback: atomic scatter, needs only (nu+ni)*D*4 bytes of ws.
        float* Zu1 = (float*)d_ws;
        float* Zi1 = Zu1 + (size_t)nu * D;
        hipMemsetAsync(d_ws, 0, (size_t)nR * D * sizeof(float), stream);

        const int threads = 256;
        long long tot = (long long)nnz * D;
        unsigned blocks = (unsigned)((tot + threads - 1) / threads);

        spmm_edge<<<blocks, threads, 0, stream>>>(vals, rows, cols, user_emb,
                                                  item_emb, Zu1, Zi1, 1.0f, nnz);
        long long nu4 = (long long)nu * D / 4;
        long long ni4 = (long long)ni * D / 4;
        combine_kernel<<<(unsigned)((nu4 + 255) / 256), 256, 0, stream>>>(
            user_emb, Zu1, out_u, nu4);
        combine_kernel<<<(unsigned)((ni4 + 255) / 256), 256, 0, stream>>>(
            item_emb, Zi1, out_i, ni4);
        spmm_edge<<<blocks, threads, 0, stream>>>(vals, rows, cols, Zu1, Zi1,
                                                  out_u, out_i, 1.0f / 3.0f, nnz);
    }
}

// Round 4
// 1414.301 us; speedup vs baseline: 5.3717x; 5.3717x over previous
//
#include <hip/hip_runtime.h>

// LightGCL forward: 2 layers of bipartite SpMM + mean of layer embeddings.
// Pipeline: bucket 10M (dest,src,val) entries into 128-row coarse buckets
// (chunk-grouped dense writes), refine each bucket in-place into 8 sub-buckets
// of 16 rows (LDS-staged), then accumulate with EXCLUSIVE per-wave ownership:
// wave w owns rows [16w,16w+16) of its bucket -> plain LDS read-add-write,
// zero atomics in the hot loop. Gather sources are bf16.

constexpr int D = 64;
constexpr int RPB = 128;            // rows per coarse bucket
constexpr int FPB = 8;              // fine (16-row) sub-buckets per bucket
constexpr int NBMAX = 2560;         // LDS histogram capacity
constexpr int REF_CAP = 8000;       // refine LDS staging capacity (entries)
constexpr int PASSB_EDGES = 16384;  // edges per block in pass_bucket

static __device__ __forceinline__ unsigned short f32_to_bf16(float f) {
    unsigned u = __float_as_uint(f);
    unsigned r = u + 0x7FFFu + ((u >> 16) & 1u);
    return (unsigned short)(r >> 16);
}
static __device__ __forceinline__ float bf16_to_f32(unsigned short h) {
    return __uint_as_float(((unsigned)h) << 16);
}

// ---------------- bucket build ----------------

__global__ void bucket_hist(const int* __restrict__ rows,
                            const int* __restrict__ cols,
                            int* __restrict__ bktCnt, int nu, int nnz, int NB) {
    __shared__ int cnt[NBMAX];
    for (int i = threadIdx.x; i < NB; i += blockDim.x) cnt[i] = 0;
    __syncthreads();
    int stride = gridDim.x * blockDim.x;
    for (int e = blockIdx.x * blockDim.x + threadIdx.x; e < nnz; e += stride) {
        atomicAdd(&cnt[rows[e] >> 7], 1);
        atomicAdd(&cnt[(nu + cols[e]) >> 7], 1);
    }
    __syncthreads();
    for (int i = threadIdx.x; i < NB; i += blockDim.x)
        if (cnt[i]) atomicAdd(&bktCnt[i], cnt[i]);
}

// Exclusive scan of bucket counts (single block, NB <= NBMAX).
__global__ void scan_buckets(const int* __restrict__ bktCnt,
                             int* __restrict__ bktBase, int* __restrict__ bktCur,
                             int NB, int total) {
    __shared__ int tsum[256];
    int t = threadIdx.x;
    const int IT = (NB + 255) / 256;  // <= 10
    int v[10];
    int s = 0;
    for (int k = 0; k < IT; k++) {
        int i = t * IT + k;
        v[k] = (i < NB) ? bktCnt[i] : 0;
        s += v[k];
    }
    tsum[t] = s;
    __syncthreads();
    for (int off = 1; off < 256; off <<= 1) {
        int x = (t >= off) ? tsum[t - off] : 0;
        __syncthreads();
        tsum[t] += x;
        __syncthreads();
    }
    int excl = (t > 0) ? tsum[t - 1] : 0;
    for (int k = 0; k < IT; k++) {
        int i = t * IT + k;
        if (i < NB) { bktBase[i] = excl; bktCur[i] = excl; excl += v[k]; }
    }
    if (t == 255) bktBase[NB] = total;
}

// Scatter entries grouped by coarse bucket; per-block chunk reservation makes
// the global writes dense. Pack: x = (rowlocal<<19) | src_global, y = val bits.
__global__ __launch_bounds__(256) void pass_bucket(
    const float* __restrict__ vals, const int* __restrict__ rows,
    const int* __restrict__ cols, int* __restrict__ bktCur,
    int2* __restrict__ tmp, int nu, int nnz, int NB) {
    __shared__ int cnt[NBMAX];
    for (int i = threadIdx.x; i < NB; i += 256) cnt[i] = 0;
    __syncthreads();
    int base = blockIdx.x * PASSB_EDGES;
    for (int k = 0; k < PASSB_EDGES / 256; k++) {
        int e = base + k * 256 + threadIdx.x;
        if (e < nnz) {
            atomicAdd(&cnt[rows[e] >> 7], 1);
            atomicAdd(&cnt[(nu + cols[e]) >> 7], 1);
        }
    }
    __syncthreads();
    for (int i = threadIdx.x; i < NB; i += 256) {
        int c = cnt[i];
        if (c) cnt[i] = atomicAdd(&bktCur[i], c);  // chunk base -> LDS cursor
    }
    __syncthreads();
    for (int k = 0; k < PASSB_EDGES / 256; k++) {
        int e = base + k * 256 + threadIdx.x;
        if (e < nnz) {
            int r = rows[e], c = cols[e];
            int iv = __float_as_int(vals[e]);
            int gi = nu + c;
            int p1 = atomicAdd(&cnt[r >> 7], 1);
            tmp[p1] = make_int2(((r & 127) << 19) | gi, iv);
            int p2 = atomicAdd(&cnt[gi >> 7], 1);
            tmp[p2] = make_int2(((gi & 127) << 19) | r, iv);
        }
    }
}

// Refine one coarse bucket in place: sort its entries into 8 sub-buckets of
// 16 rows, via LDS staging (no cross-block interaction). fine = x>>23.
// Oversized buckets (> REF_CAP, statistically impossible here) are left
// unsorted and flagged with a negative sentinel in fineBase[b*FPB].
__global__ __launch_bounds__(512) void refine_kernel(
    int2* __restrict__ tmp, const int* __restrict__ bktBase,
    int* __restrict__ fineBase, int NB) {
    __shared__ int2 stage[REF_CAP];
    __shared__ int h[FPB], cur[FPB];
    int b = blockIdx.x;
    int beg = bktBase[b], end = bktBase[b + 1];
    int n = end - beg;
    int t = threadIdx.x;
    if (t < FPB) h[t] = 0;
    __syncthreads();
    if (n <= REF_CAP) {
        for (int e = t; e < n; e += 512) {
            int2 v = tmp[beg + e];
            stage[e] = v;
            atomicAdd(&h[(v.x >> 23) & (FPB - 1)], 1);
        }
        __syncthreads();
        if (t == 0) {
            int s = beg;
            for (int k = 0; k < FPB; k++) {
                cur[k] = s;
                fineBase[b * FPB + k] = s;
                s += h[k];
            }
        }
        __syncthreads();
        for (int e = t; e < n; e += 512) {
            int2 v = stage[e];
            int p = atomicAdd(&cur[(v.x >> 23) & (FPB - 1)], 1);
            tmp[p] = v;
        }
    } else {
        if (t < FPB) fineBase[b * FPB + t] = (t == 0) ? -(beg + 1) : 0;
    }
}

// Concat + convert f32 embeddings -> bf16 table [nR][D].
__global__ void convert_e0(const float* __restrict__ Eu,
                           const float* __restrict__ Ei,
                           unsigned short* __restrict__ Ecat,
                           long long nuD, long long nD) {
    long long stride = (long long)gridDim.x * blockDim.x * 4;
    for (long long i = ((long long)blockIdx.x * blockDim.x + threadIdx.x) * 4;
         i < nD; i += stride) {
        const float* src = (i < nuD) ? (Eu + i) : (Ei + (i - nuD));
        float4 f = *(const float4*)src;
        unsigned short o0 = f32_to_bf16(f.x), o1 = f32_to_bf16(f.y);
        unsigned short o2 = f32_to_bf16(f.z), o3 = f32_to_bf16(f.w);
        *(uint2*)(Ecat + i) =
            make_uint2(((unsigned)o1 << 16) | o0, ((unsigned)o3 << 16) | o2);
    }
}

// ---------------- accumulate (the SpMM) ----------------
// One block per coarse bucket; 32KB LDS f32 accumulator [128][64].
// Wave w EXCLUSIVELY owns rows [16w,16w+16): plain LDS read-add-write,
// no atomics. Unroll-2 keeps two gathers in flight.
template <bool FUSE>
__global__ __launch_bounds__(512) void accum2_kernel(
    const int2* __restrict__ tmp, const int* __restrict__ bktBase,
    const int* __restrict__ fineBase,
    const unsigned short* __restrict__ gsrc,  // bf16 [nR][D] gather source
    const float* __restrict__ Eu0, const float* __restrict__ Ei0,
    const unsigned short* __restrict__ Z1,
    unsigned short* __restrict__ Zout,
    float* __restrict__ out_u, float* __restrict__ out_i,
    int nu, int nR) {
    __shared__ float acc[RPB * D];  // 32768 bytes
    for (int i = threadIdx.x; i < RPB * D; i += 512) acc[i] = 0.f;
    __syncthreads();

    int b = blockIdx.x;
    int w = threadIdx.x >> 6, lane = threadIdx.x & 63;
    int fb0 = fineBase[b * FPB];
    float* ap = acc + lane;
    if (fb0 >= 0) {
        int fb = fineBase[b * FPB + w];
        int fe = (w < FPB - 1) ? fineBase[b * FPB + w + 1] : bktBase[b + 1];
        int e = fb;
        for (; e + 2 <= fe; e += 2) {
            int2 s0 = tmp[e];
            int2 s1 = tmp[e + 1];
            float g0 = bf16_to_f32(gsrc[(long long)(s0.x & 0x7FFFF) * D + lane]);
            float g1 = bf16_to_f32(gsrc[(long long)(s1.x & 0x7FFFF) * D + lane]);
            ap[(s0.x >> 19) << 6] += __int_as_float(s0.y) * g0;
            ap[(s1.x >> 19) << 6] += __int_as_float(s1.y) * g1;
        }
        if (e < fe) {
            int2 s0 = tmp[e];
            float g0 = bf16_to_f32(gsrc[(long long)(s0.x & 0x7FFFF) * D + lane]);
            ap[(s0.x >> 19) << 6] += __int_as_float(s0.y) * g0;
        }
    } else {
        // unsorted oversized bucket: every wave scans all, keeps its rows
        int beg = -(fb0 + 1), end = bktBase[b + 1];
        for (int e = beg; e < end; e++) {
            int2 s = tmp[e];
            int rl = s.x >> 19;
            if ((rl >> 4) != w) continue;
            float g = bf16_to_f32(gsrc[(long long)(s.x & 0x7FFFF) * D + lane]);
            ap[rl << 6] += __int_as_float(s.y) * g;
        }
    }
    __syncthreads();

    // epilogue: 512 threads -> 128 rows x 4 chunks of 16 dims
    int rl = threadIdx.x >> 2;
    int d0 = (threadIdx.x & 3) * 16;
    int gr = b * RPB + rl;
    if (gr >= nR) return;
    const float* apo = &acc[rl * D + d0];
    if (!FUSE) {
        unsigned short* dst = Zout + (long long)gr * D + d0;
#pragma unroll
        for (int j = 0; j < 16; j += 2) {
            unsigned a = f32_to_bf16(apo[j]);
            unsigned c = f32_to_bf16(apo[j + 1]);
            *(unsigned*)(dst + j) = (c << 16) | a;
        }
    } else {
        const float* e0 = (gr < nu) ? (Eu0 + (long long)gr * D + d0)
                                    : (Ei0 + (long long)(gr - nu) * D + d0);
        const unsigned short* z1 = Z1 + (long long)gr * D + d0;
        float* dst = (gr < nu) ? (out_u + (long long)gr * D + d0)
                               : (out_i + (long long)(gr - nu) * D + d0);
        const float inv3 = 1.f / 3.f;
#pragma unroll
        for (int j = 0; j < 16; j += 4) {
            float4 a = *(const float4*)(e0 + j);
            float4 o;
            o.x = (a.x + bf16_to_f32(z1[j + 0]) + apo[j + 0]) * inv3;
            o.y = (a.y + bf16_to_f32(z1[j + 1]) + apo[j + 1]) * inv3;
            o.z = (a.z + bf16_to_f32(z1[j + 2]) + apo[j + 2]) * inv3;
            o.w = (a.w + bf16_to_f32(z1[j + 3]) + apo[j + 3]) * inv3;
            *(float4*)(dst + j) = o;
        }
    }
}

// ---------------- fallback (atomic scatter, needs only 77 MB ws) ----------------

__global__ void spmm_edge(const float* __restrict__ vals,
                          const int* __restrict__ rows,
                          const int* __restrict__ cols,
                          const float* __restrict__ Eu,
                          const float* __restrict__ Ei,
                          float* __restrict__ Zu, float* __restrict__ Zi,
                          float scale, int nnz) {
    long long gid = (long long)blockIdx.x * blockDim.x + threadIdx.x;
    if (gid >= (long long)nnz * D) return;
    int e = (int)(gid >> 6);
    int d = (int)(gid & 63);
    float v = vals[e] * scale;
    long long r = rows[e];
    long long c = cols[e];
    atomicAdd(&Zu[r * D + d], v * Ei[c * D + d]);
    atomicAdd(&Zi[c * D + d], v * Eu[r * D + d]);
}

__global__ void combine_kernel(const float* __restrict__ E0,
                               const float* __restrict__ Z1,
                               float* __restrict__ out, long long n4) {
    long long i = (long long)blockIdx.x * blockDim.x + threadIdx.x;
    if (i >= n4) return;
    const float4 a = reinterpret_cast<const float4*>(E0)[i];
    const float4 b = reinterpret_cast<const float4*>(Z1)[i];
    const float inv3 = 1.0f / 3.0f;
    float4 o;
    o.x = (a.x + b.x) * inv3;
    o.y = (a.y + b.y) * inv3;
    o.z = (a.z + b.z) * inv3;
    o.w = (a.w + b.w) * inv3;
    reinterpret_cast<float4*>(out)[i] = o;
}

// ---------------- launcher ----------------

static inline size_t align256(size_t x) { return (x + 255) & ~(size_t)255; }

extern "C" void kernel_launch(void* const* d_in, const int* in_sizes, int n_in,
                              void* d_out, int out_size, void* d_ws, size_t ws_size,
                              hipStream_t stream) {
    const float* user_emb = (const float*)d_in[0];
    const float* item_emb = (const float*)d_in[1];
    const float* vals     = (const float*)d_in[2];
    const int*   rows     = (const int*)d_in[3];
    const int*   cols     = (const int*)d_in[4];

    const int nu  = in_sizes[0] / D;  // 100000
    const int ni  = in_sizes[1] / D;  // 200000
    const int nnz = in_sizes[2];      // 5000000
    const int nR  = nu + ni;
    const int NB  = (nR + RPB - 1) / RPB;  // 2344

    float* out_u = (float*)d_out;
    float* out_i = out_u + (size_t)nu * D;

    // ws layout
    size_t off = 0;
    size_t o_tmp  = off; off += align256((size_t)2 * nnz * sizeof(int2));
    size_t o_E    = off; off += align256((size_t)nR * D * sizeof(unsigned short));
    size_t o_Z1   = off; off += align256((size_t)nR * D * sizeof(unsigned short));
    size_t o_cnt  = off; off += align256((size_t)(NB + 1) * sizeof(int));
    size_t o_base = off; off += align256((size_t)(NB + 2) * sizeof(int));
    size_t o_cur  = off; off += align256((size_t)(NB + 1) * sizeof(int));
    size_t o_fine = off; off += align256((size_t)NB * FPB * sizeof(int));
    size_t needed = off;

    bool fits19 = (nR < (1 << 19));  // src index must pack in 19 bits

    if (ws_size >= needed && NB <= NBMAX && fits19) {
        char* w = (char*)d_ws;
        int2*           tmp      = (int2*)(w + o_tmp);
        unsigned short* Ecat     = (unsigned short*)(w + o_E);
        unsigned short* Z1bf     = (unsigned short*)(w + o_Z1);
        int*            bktCnt   = (int*)(w + o_cnt);
        int*            bktBase  = (int*)(w + o_base);
        int*            bktCur   = (int*)(w + o_cur);
        int*            fineBase = (int*)(w + o_fine);

        hipMemsetAsync(bktCnt, 0, (size_t)NB * sizeof(int), stream);

        bucket_hist<<<512, 256, 0, stream>>>(rows, cols, bktCnt, nu, nnz, NB);
        scan_buckets<<<1, 256, 0, stream>>>(bktCnt, bktBase, bktCur, NB, 2 * nnz);

        unsigned gB = (unsigned)((nnz + PASSB_EDGES - 1) / PASSB_EDGES);
        pass_bucket<<<gB, 256, 0, stream>>>(vals, rows, cols, bktCur, tmp,
                                            nu, nnz, NB);
        refine_kernel<<<NB, 512, 0, stream>>>(tmp, bktBase, fineBase, NB);

        long long nD = (long long)nR * D;
        long long nuD = (long long)nu * D;
        unsigned gC = (unsigned)((nD / 4 + 255) / 256);
        if (gC > 4096) gC = 4096;
        convert_e0<<<gC, 256, 0, stream>>>(user_emb, item_emb, Ecat, nuD, nD);

        // Layer 1: Z1 = A_cat @ E0
        accum2_kernel<false><<<NB, 512, 0, stream>>>(
            tmp, bktBase, fineBase, Ecat, nullptr, nullptr, nullptr, Z1bf,
            nullptr, nullptr, nu, nR);
        // Layer 2 + combine: out = (E0 + Z1 + A_cat @ Z1) / 3
        accum2_kernel<true><<<NB, 512, 0, stream>>>(
            tmp, bktBase, fineBase, Z1bf, user_emb, item_emb, Z1bf, nullptr,
            out_u, out_i, nu, nR);
    } else {
        // Fallback: atomic scatter, needs only (nu+ni)*D*4 bytes of ws.
        float* Zu1 = (float*)d_ws;
        float* Zi1 = Zu1 + (size_t)nu * D;
        hipMemsetAsync(d_ws, 0, (size_t)nR * D * sizeof(float), stream);

        const int threads = 256;
        long long tot = (long long)nnz * D;
        unsigned blocks = (unsigned)((tot + threads - 1) / threads);

        spmm_edge<<<blocks, threads, 0, stream>>>(vals, rows, cols, user_emb,
                                                  item_emb, Zu1, Zi1, 1.0f, nnz);
        long long nu4 = (long long)nu * D / 4;
        long long ni4 = (long long)ni * D / 4;
        combine_kernel<<<(unsigned)((nu4 + 255) / 256), 256, 0, stream>>>(
            user_emb, Zu1, out_u, nu4);
        combine_kernel<<<(unsigned)((ni4 + 255) / 256), 256, 0, stream>>>(
            item_emb, Zi1, out_i, ni4);
        spmm_edge<<<blocks, threads, 0, stream>>>(vals, rows, cols, Zu1, Zi1,
                                                  out_u, out_i, 1.0f / 3.0f, nnz);
    }
}

// Round 5
// 1083.051 us; speedup vs baseline: 7.0146x; 1.3058x over previous
//
#include <hip/hip_runtime.h>

// LightGCL forward: 2 layers of bipartite SpMM + mean of layer embeddings.
// Pipeline: bucket 10M (dest,src,val) entries into 128-row coarse buckets
// (chunk-grouped dense writes), refine each bucket in-place sorted by ROW
// (128 bins, LDS-staged), then accumulate with REGISTER accumulators:
// each wave owns 16 rows, processes them one row at a time (lane = dim,
// 4 partial sums, 4 gathers in flight), writes the finished row straight
// to global. No LDS and no atomics anywhere in the hot loop.

constexpr int D = 64;
constexpr int RPB = 128;            // rows per coarse bucket
constexpr int NBMAX = 2560;         // LDS histogram capacity
constexpr int REF_CAP = 8000;       // refine LDS staging capacity (entries)
constexpr int PASSB_EDGES = 16384;  // edges per block in pass_bucket

static __device__ __forceinline__ unsigned short f32_to_bf16(float f) {
    unsigned u = __float_as_uint(f);
    unsigned r = u + 0x7FFFu + ((u >> 16) & 1u);
    return (unsigned short)(r >> 16);
}
static __device__ __forceinline__ float bf16_to_f32(unsigned short h) {
    return __uint_as_float(((unsigned)h) << 16);
}

// ---------------- bucket build ----------------

__global__ void bucket_hist(const int* __restrict__ rows,
                            const int* __restrict__ cols,
                            int* __restrict__ bktCnt, int nu, int nnz, int NB) {
    __shared__ int cnt[NBMAX];
    for (int i = threadIdx.x; i < NB; i += blockDim.x) cnt[i] = 0;
    __syncthreads();
    int stride = gridDim.x * blockDim.x;
    for (int e = blockIdx.x * blockDim.x + threadIdx.x; e < nnz; e += stride) {
        atomicAdd(&cnt[rows[e] >> 7], 1);
        atomicAdd(&cnt[(nu + cols[e]) >> 7], 1);
    }
    __syncthreads();
    for (int i = threadIdx.x; i < NB; i += blockDim.x)
        if (cnt[i]) atomicAdd(&bktCnt[i], cnt[i]);
}

// Exclusive scan of bucket counts (single block, NB <= NBMAX).
__global__ void scan_buckets(const int* __restrict__ bktCnt,
                             int* __restrict__ bktBase, int* __restrict__ bktCur,
                             int NB, int total) {
    __shared__ int tsum[256];
    int t = threadIdx.x;
    const int IT = (NB + 255) / 256;  // <= 10
    int v[10];
    int s = 0;
    for (int k = 0; k < IT; k++) {
        int i = t * IT + k;
        v[k] = (i < NB) ? bktCnt[i] : 0;
        s += v[k];
    }
    tsum[t] = s;
    __syncthreads();
    for (int off = 1; off < 256; off <<= 1) {
        int x = (t >= off) ? tsum[t - off] : 0;
        __syncthreads();
        tsum[t] += x;
        __syncthreads();
    }
    int excl = (t > 0) ? tsum[t - 1] : 0;
    for (int k = 0; k < IT; k++) {
        int i = t * IT + k;
        if (i < NB) { bktBase[i] = excl; bktCur[i] = excl; excl += v[k]; }
    }
    if (t == 255) bktBase[NB] = total;
}

// Scatter entries grouped by coarse bucket; per-block chunk reservation makes
// the global writes dense. Pack: x = (rowlocal<<19) | src_global, y = val bits.
__global__ __launch_bounds__(256) void pass_bucket(
    const float* __restrict__ vals, const int* __restrict__ rows,
    const int* __restrict__ cols, int* __restrict__ bktCur,
    int2* __restrict__ tmp, int nu, int nnz, int NB) {
    __shared__ int cnt[NBMAX];
    for (int i = threadIdx.x; i < NB; i += 256) cnt[i] = 0;
    __syncthreads();
    int base = blockIdx.x * PASSB_EDGES;
    for (int k = 0; k < PASSB_EDGES / 256; k++) {
        int e = base + k * 256 + threadIdx.x;
        if (e < nnz) {
            atomicAdd(&cnt[rows[e] >> 7], 1);
            atomicAdd(&cnt[(nu + cols[e]) >> 7], 1);
        }
    }
    __syncthreads();
    for (int i = threadIdx.x; i < NB; i += 256) {
        int c = cnt[i];
        if (c) cnt[i] = atomicAdd(&bktCur[i], c);  // chunk base -> LDS cursor
    }
    __syncthreads();
    for (int k = 0; k < PASSB_EDGES / 256; k++) {
        int e = base + k * 256 + threadIdx.x;
        if (e < nnz) {
            int r = rows[e], c = cols[e];
            int iv = __float_as_int(vals[e]);
            int gi = nu + c;
            int p1 = atomicAdd(&cnt[r >> 7], 1);
            tmp[p1] = make_int2(((r & 127) << 19) | gi, iv);
            int p2 = atomicAdd(&cnt[gi >> 7], 1);
            tmp[p2] = make_int2(((gi & 127) << 19) | r, iv);
        }
    }
}

// Refine one coarse bucket in place: sort its entries by local row (128 bins)
// via LDS staging. rowBase[b*RPB + r] = start of row r's segment.
// Oversized buckets (> REF_CAP, +57 sigma, never for this input) keep a
// negative sentinel in rowBase[b*RPB] and are handled by a scan fallback.
__global__ __launch_bounds__(512) void refine_kernel(
    int2* __restrict__ tmp, const int* __restrict__ bktBase,
    int* __restrict__ rowBase, int NB) {
    __shared__ int2 stage[REF_CAP];
    __shared__ int h[RPB], cur[RPB];
    int b = blockIdx.x;
    int beg = bktBase[b], end = bktBase[b + 1];
    int n = end - beg;
    int t = threadIdx.x;
    if (t < RPB) h[t] = 0;
    __syncthreads();
    if (n <= REF_CAP) {
        for (int e = t; e < n; e += 512) {
            int2 v = tmp[beg + e];
            stage[e] = v;
            atomicAdd(&h[(v.x >> 19) & (RPB - 1)], 1);
        }
        __syncthreads();
        int myc = (t < RPB) ? h[t] : 0;
        // Hillis-Steele inclusive scan over 128 bins
        for (int off = 1; off < RPB; off <<= 1) {
            int x = 0;
            if (t < RPB && t >= off) x = h[t - off];
            __syncthreads();
            if (t < RPB) h[t] += x;
            __syncthreads();
        }
        if (t < RPB) {
            int excl = beg + h[t] - myc;
            cur[t] = excl;
            rowBase[(size_t)b * RPB + t] = excl;
        }
        __syncthreads();
        for (int e = t; e < n; e += 512) {
            int2 v = stage[e];
            int p = atomicAdd(&cur[(v.x >> 19) & (RPB - 1)], 1);
            tmp[p] = v;
        }
    } else {
        if (t < RPB) rowBase[(size_t)b * RPB + t] = (t == 0) ? -(beg + 1) : 0;
    }
}

// Concat + convert f32 embeddings -> bf16 table [nR][D].
__global__ void convert_e0(const float* __restrict__ Eu,
                           const float* __restrict__ Ei,
                           unsigned short* __restrict__ Ecat,
                           long long nuD, long long nD) {
    long long stride = (long long)gridDim.x * blockDim.x * 4;
    for (long long i = ((long long)blockIdx.x * blockDim.x + threadIdx.x) * 4;
         i < nD; i += stride) {
        const float* src = (i < nuD) ? (Eu + i) : (Ei + (i - nuD));
        float4 f = *(const float4*)src;
        unsigned short o0 = f32_to_bf16(f.x), o1 = f32_to_bf16(f.y);
        unsigned short o2 = f32_to_bf16(f.z), o3 = f32_to_bf16(f.w);
        *(uint2*)(Ecat + i) =
            make_uint2(((unsigned)o1 << 16) | o0, ((unsigned)o3 << 16) | o2);
    }
}

// ---------------- accumulate (the SpMM) ----------------
// One block per coarse bucket, 8 waves; wave w owns rows [16w,16w+16).
// Rows processed one at a time: lane = dim, accumulate in 4 register partial
// sums, 4 gathers in flight; finished row written straight to global.
// FUSE=false: Zout_bf16[row] = sum           (layer 1)
// FUSE=true : out[row] = (E0 + Z1 + sum)/3   (layer 2 + combine)
template <bool FUSE>
__global__ __launch_bounds__(512) void accum3_kernel(
    const int2* __restrict__ tmp, const int* __restrict__ bktBase,
    const int* __restrict__ rowBase,
    const unsigned short* __restrict__ gsrc,  // bf16 [nR][D] gather source
    const float* __restrict__ Eu0, const float* __restrict__ Ei0,
    const unsigned short* __restrict__ Z1,
    unsigned short* __restrict__ Zout,
    float* __restrict__ out,  // [nR][D] f32 (concatenated users+items)
    int nu, int nR) {
    int b = blockIdx.x;
    int w = threadIdx.x >> 6, lane = threadIdx.x & 63;
    int bEnd = bktBase[b + 1];
    int rb0 = rowBase[(size_t)b * RPB];
    bool sorted = (rb0 >= 0);

    for (int k = 0; k < 16; k++) {
        int rl = (w << 4) + k;
        int gr = b * RPB + rl;
        if (gr >= nR) break;
        float a0 = 0.f, a1 = 0.f, a2 = 0.f, a3 = 0.f;
        if (sorted) {
            int e   = rowBase[(size_t)b * RPB + rl];
            int end = (rl < RPB - 1) ? rowBase[(size_t)b * RPB + rl + 1] : bEnd;
            for (; e + 4 <= end; e += 4) {
                int2 s0 = tmp[e], s1 = tmp[e + 1], s2 = tmp[e + 2], s3 = tmp[e + 3];
                float g0 = bf16_to_f32(gsrc[(size_t)(s0.x & 0x7FFFF) * D + lane]);
                float g1 = bf16_to_f32(gsrc[(size_t)(s1.x & 0x7FFFF) * D + lane]);
                float g2 = bf16_to_f32(gsrc[(size_t)(s2.x & 0x7FFFF) * D + lane]);
                float g3 = bf16_to_f32(gsrc[(size_t)(s3.x & 0x7FFFF) * D + lane]);
                a0 += __int_as_float(s0.y) * g0;
                a1 += __int_as_float(s1.y) * g1;
                a2 += __int_as_float(s2.y) * g2;
                a3 += __int_as_float(s3.y) * g3;
            }
            for (; e < end; e++) {
                int2 s = tmp[e];
                a0 += __int_as_float(s.y) *
                      bf16_to_f32(gsrc[(size_t)(s.x & 0x7FFFF) * D + lane]);
            }
        } else {
            // unsorted oversized bucket (never expected): scan + filter
            int beg = -(rb0 + 1);
            for (int e = beg; e < bEnd; e++) {
                int2 s = tmp[e];
                if (((s.x >> 19) & (RPB - 1)) != rl) continue;
                a0 += __int_as_float(s.y) *
                      bf16_to_f32(gsrc[(size_t)(s.x & 0x7FFFF) * D + lane]);
            }
        }
        float acc = (a0 + a1) + (a2 + a3);
        long long o = (long long)gr * D + lane;
        if (!FUSE) {
            Zout[o] = f32_to_bf16(acc);
        } else {
            float e0 = (gr < nu) ? Eu0[o]
                                 : Ei0[(long long)(gr - nu) * D + lane];
            out[o] = (e0 + bf16_to_f32(Z1[o]) + acc) * (1.f / 3.f);
        }
    }
}

// ---------------- fallback (atomic scatter, needs only 77 MB ws) ----------------

__global__ void spmm_edge(const float* __restrict__ vals,
                          const int* __restrict__ rows,
                          const int* __restrict__ cols,
                          const float* __restrict__ Eu,
                          const float* __restrict__ Ei,
                          float* __restrict__ Zu, float* __restrict__ Zi,
                          float scale, int nnz) {
    long long gid = (long long)blockIdx.x * blockDim.x + threadIdx.x;
    if (gid >= (long long)nnz * D) return;
    int e = (int)(gid >> 6);
    int d = (int)(gid & 63);
    float v = vals[e] * scale;
    long long r = rows[e];
    long long c = cols[e];
    atomicAdd(&Zu[r * D + d], v * Ei[c * D + d]);
    atomicAdd(&Zi[c * D + d], v * Eu[r * D + d]);
}

__global__ void combine_kernel(const float* __restrict__ E0,
                               const float* __restrict__ Z1,
                               float* __restrict__ out, long long n4) {
    long long i = (long long)blockIdx.x * blockDim.x + threadIdx.x;
    if (i >= n4) return;
    const float4 a = reinterpret_cast<const float4*>(E0)[i];
    const float4 b = reinterpret_cast<const float4*>(Z1)[i];
    const float inv3 = 1.0f / 3.0f;
    float4 o;
    o.x = (a.x + b.x) * inv3;
    o.y = (a.y + b.y) * inv3;
    o.z = (a.z + b.z) * inv3;
    o.w = (a.w + b.w) * inv3;
    reinterpret_cast<float4*>(out)[i] = o;
}

// ---------------- launcher ----------------

static inline size_t align256(size_t x) { return (x + 255) & ~(size_t)255; }

extern "C" void kernel_launch(void* const* d_in, const int* in_sizes, int n_in,
                              void* d_out, int out_size, void* d_ws, size_t ws_size,
                              hipStream_t stream) {
    const float* user_emb = (const float*)d_in[0];
    const float* item_emb = (const float*)d_in[1];
    const float* vals     = (const float*)d_in[2];
    const int*   rows     = (const int*)d_in[3];
    const int*   cols     = (const int*)d_in[4];

    const int nu  = in_sizes[0] / D;  // 100000
    const int ni  = in_sizes[1] / D;  // 200000
    const int nnz = in_sizes[2];      // 5000000
    const int nR  = nu + ni;
    const int NB  = (nR + RPB - 1) / RPB;  // 2344

    float* out = (float*)d_out;  // [nR][D], users then items

    // ws layout
    size_t off = 0;
    size_t o_tmp  = off; off += align256((size_t)2 * nnz * sizeof(int2));
    size_t o_E    = off; off += align256((size_t)nR * D * sizeof(unsigned short));
    size_t o_Z1   = off; off += align256((size_t)nR * D * sizeof(unsigned short));
    size_t o_cnt  = off; off += align256((size_t)(NB + 1) * sizeof(int));
    size_t o_base = off; off += align256((size_t)(NB + 2) * sizeof(int));
    size_t o_cur  = off; off += align256((size_t)(NB + 1) * sizeof(int));
    size_t o_row  = off; off += align256((size_t)NB * RPB * sizeof(int));
    size_t needed = off;

    bool fits19 = (nR < (1 << 19));  // src index must pack in 19 bits

    if (ws_size >= needed && NB <= NBMAX && fits19) {
        char* w = (char*)d_ws;
        int2*           tmp      = (int2*)(w + o_tmp);
        unsigned short* Ecat     = (unsigned short*)(w + o_E);
        unsigned short* Z1bf     = (unsigned short*)(w + o_Z1);
        int*            bktCnt   = (int*)(w + o_cnt);
        int*            bktBase  = (int*)(w + o_base);
        int*            bktCur   = (int*)(w + o_cur);
        int*            rowBase  = (int*)(w + o_row);

        hipMemsetAsync(bktCnt, 0, (size_t)NB * sizeof(int), stream);

        bucket_hist<<<512, 256, 0, stream>>>(rows, cols, bktCnt, nu, nnz, NB);
        scan_buckets<<<1, 256, 0, stream>>>(bktCnt, bktBase, bktCur, NB, 2 * nnz);

        unsigned gB = (unsigned)((nnz + PASSB_EDGES - 1) / PASSB_EDGES);
        pass_bucket<<<gB, 256, 0, stream>>>(vals, rows, cols, bktCur, tmp,
                                            nu, nnz, NB);
        refine_kernel<<<NB, 512, 0, stream>>>(tmp, bktBase, rowBase, NB);

        long long nD = (long long)nR * D;
        long long nuD = (long long)nu * D;
        unsigned gC = (unsigned)((nD / 4 + 255) / 256);
        if (gC > 4096) gC = 4096;
        convert_e0<<<gC, 256, 0, stream>>>(user_emb, item_emb, Ecat, nuD, nD);

        // Layer 1: Z1 = A_cat @ E0
        accum3_kernel<false><<<NB, 512, 0, stream>>>(
            tmp, bktBase, rowBase, Ecat, nullptr, nullptr, nullptr, Z1bf,
            nullptr, nu, nR);
        // Layer 2 + combine: out = (E0 + Z1 + A_cat @ Z1) / 3
        accum3_kernel<true><<<NB, 512, 0, stream>>>(
            tmp, bktBase, rowBase, Z1bf, user_emb, item_emb, Z1bf, nullptr,
            out, nu, nR);
    } else {
        // Fallback: atomic scatter, needs only (nu+ni)*D*4 bytes of ws.
        float* Zu1 = (float*)d_ws;
        float* Zi1 = Zu1 + (size_t)nu * D;
        float* out_u = out;
        float* out_i = out + (size_t)nu * D;
        hipMemsetAsync(d_ws, 0, (size_t)nR * D * sizeof(float), stream);

        const int threads = 256;
        long long tot = (long long)nnz * D;
        unsigned blocks = (unsigned)((tot + threads - 1) / threads);

        spmm_edge<<<blocks, threads, 0, stream>>>(vals, rows, cols, user_emb,
                                                  item_emb, Zu1, Zi1, 1.0f, nnz);
        long long nu4 = (long long)nu * D / 4;
        long long ni4 = (long long)ni * D / 4;
        combine_kernel<<<(unsigned)((nu4 + 255) / 256), 256, 0, stream>>>(
            user_emb, Zu1, out_u, nu4);
        combine_kernel<<<(unsigned)((ni4 + 255) / 256), 256, 0, stream>>>(
            item_emb, Zi1, out_i, ni4);
        spmm_edge<<<blocks, threads, 0, stream>>>(vals, rows, cols, Zu1, Zi1,
                                                  out_u, out_i, 1.0f / 3.0f, nnz);
    }
}

// Round 6
// 795.530 us; speedup vs baseline: 9.5499x; 1.3614x over previous
//
#include <hip/hip_runtime.h>

// LightGCL forward: 2 layers of bipartite SpMM + mean of layer embeddings.
// Pipeline: bucket 10M (dest,src,val) entries into 128-row coarse buckets
// (chunk-grouped dense writes), refine each bucket in-place sorted by ROW
// (128 bins, LDS-staged), then accumulate with quarter-wave entry streams:
// lane (q,m) gathers dims [4m,4m+4) of entry e0+q (uint2 = 4 bf16), so one
// wave instruction covers 4 entries; each wave runs TWO rows concurrently
// for independent latency chains. shfl_xor reduces across quarters at row
// end. No atomics and no LDS in the hot loop.

constexpr int D = 64;
constexpr int RPB = 128;            // rows per coarse bucket
constexpr int NBMAX = 2560;         // LDS histogram capacity
constexpr int REF_CAP = 8000;       // refine LDS staging capacity (entries)
constexpr int PASSB_EDGES = 16384;  // edges per block in pass_bucket

static __device__ __forceinline__ unsigned short f32_to_bf16(float f) {
    unsigned u = __float_as_uint(f);
    unsigned r = u + 0x7FFFu + ((u >> 16) & 1u);
    return (unsigned short)(r >> 16);
}
static __device__ __forceinline__ float bf16_lo(unsigned g) {
    return __uint_as_float(g << 16);
}
static __device__ __forceinline__ float bf16_hi(unsigned g) {
    return __uint_as_float(g & 0xFFFF0000u);
}
static __device__ __forceinline__ float bf16_to_f32(unsigned short h) {
    return __uint_as_float(((unsigned)h) << 16);
}

// ---------------- bucket build ----------------

__global__ void bucket_hist(const int* __restrict__ rows,
                            const int* __restrict__ cols,
                            int* __restrict__ bktCnt, int nu, int nnz, int NB) {
    __shared__ int cnt[NBMAX];
    for (int i = threadIdx.x; i < NB; i += blockDim.x) cnt[i] = 0;
    __syncthreads();
    int stride = gridDim.x * blockDim.x;
    for (int e = blockIdx.x * blockDim.x + threadIdx.x; e < nnz; e += stride) {
        atomicAdd(&cnt[rows[e] >> 7], 1);
        atomicAdd(&cnt[(nu + cols[e]) >> 7], 1);
    }
    __syncthreads();
    for (int i = threadIdx.x; i < NB; i += blockDim.x)
        if (cnt[i]) atomicAdd(&bktCnt[i], cnt[i]);
}

// Exclusive scan of bucket counts (single block, NB <= NBMAX).
__global__ void scan_buckets(const int* __restrict__ bktCnt,
                             int* __restrict__ bktBase, int* __restrict__ bktCur,
                             int NB, int total) {
    __shared__ int tsum[256];
    int t = threadIdx.x;
    const int IT = (NB + 255) / 256;  // <= 10
    int v[10];
    int s = 0;
    for (int k = 0; k < IT; k++) {
        int i = t * IT + k;
        v[k] = (i < NB) ? bktCnt[i] : 0;
        s += v[k];
    }
    tsum[t] = s;
    __syncthreads();
    for (int off = 1; off < 256; off <<= 1) {
        int x = (t >= off) ? tsum[t - off] : 0;
        __syncthreads();
        tsum[t] += x;
        __syncthreads();
    }
    int excl = (t > 0) ? tsum[t - 1] : 0;
    for (int k = 0; k < IT; k++) {
        int i = t * IT + k;
        if (i < NB) { bktBase[i] = excl; bktCur[i] = excl; excl += v[k]; }
    }
    if (t == 255) bktBase[NB] = total;
}

// Scatter entries grouped by coarse bucket; per-block chunk reservation makes
// the global writes dense. Pack: x = (rowlocal<<19) | src_global, y = val bits.
__global__ __launch_bounds__(256) void pass_bucket(
    const float* __restrict__ vals, const int* __restrict__ rows,
    const int* __restrict__ cols, int* __restrict__ bktCur,
    int2* __restrict__ tmp, int nu, int nnz, int NB) {
    __shared__ int cnt[NBMAX];
    for (int i = threadIdx.x; i < NB; i += 256) cnt[i] = 0;
    __syncthreads();
    int base = blockIdx.x * PASSB_EDGES;
    for (int k = 0; k < PASSB_EDGES / 256; k++) {
        int e = base + k * 256 + threadIdx.x;
        if (e < nnz) {
            atomicAdd(&cnt[rows[e] >> 7], 1);
            atomicAdd(&cnt[(nu + cols[e]) >> 7], 1);
        }
    }
    __syncthreads();
    for (int i = threadIdx.x; i < NB; i += 256) {
        int c = cnt[i];
        if (c) cnt[i] = atomicAdd(&bktCur[i], c);  // chunk base -> LDS cursor
    }
    __syncthreads();
    for (int k = 0; k < PASSB_EDGES / 256; k++) {
        int e = base + k * 256 + threadIdx.x;
        if (e < nnz) {
            int r = rows[e], c = cols[e];
            int iv = __float_as_int(vals[e]);
            int gi = nu + c;
            int p1 = atomicAdd(&cnt[r >> 7], 1);
            tmp[p1] = make_int2(((r & 127) << 19) | gi, iv);
            int p2 = atomicAdd(&cnt[gi >> 7], 1);
            tmp[p2] = make_int2(((gi & 127) << 19) | r, iv);
        }
    }
}

// Refine one coarse bucket in place: sort its entries by local row (128 bins)
// via LDS staging. rowBase[b*RPB + r] = start of row r's segment.
// Oversized buckets (> REF_CAP, +57 sigma, never for this input) keep a
// negative sentinel in rowBase[b*RPB] and are handled by a scan fallback.
__global__ __launch_bounds__(512) void refine_kernel(
    int2* __restrict__ tmp, const int* __restrict__ bktBase,
    int* __restrict__ rowBase, int NB) {
    __shared__ int2 stage[REF_CAP];
    __shared__ int h[RPB], cur[RPB];
    int b = blockIdx.x;
    int beg = bktBase[b], end = bktBase[b + 1];
    int n = end - beg;
    int t = threadIdx.x;
    if (t < RPB) h[t] = 0;
    __syncthreads();
    if (n <= REF_CAP) {
        for (int e = t; e < n; e += 512) {
            int2 v = tmp[beg + e];
            stage[e] = v;
            atomicAdd(&h[(v.x >> 19) & (RPB - 1)], 1);
        }
        __syncthreads();
        int myc = (t < RPB) ? h[t] : 0;
        // Hillis-Steele inclusive scan over 128 bins
        for (int off = 1; off < RPB; off <<= 1) {
            int x = 0;
            if (t < RPB && t >= off) x = h[t - off];
            __syncthreads();
            if (t < RPB) h[t] += x;
            __syncthreads();
        }
        if (t < RPB) {
            int excl = beg + h[t] - myc;
            cur[t] = excl;
            rowBase[(size_t)b * RPB + t] = excl;
        }
        __syncthreads();
        for (int e = t; e < n; e += 512) {
            int2 v = stage[e];
            int p = atomicAdd(&cur[(v.x >> 19) & (RPB - 1)], 1);
            tmp[p] = v;
        }
    } else {
        if (t < RPB) rowBase[(size_t)b * RPB + t] = (t == 0) ? -(beg + 1) : 0;
    }
}

// Concat + convert f32 embeddings -> bf16 table [nR][D].
__global__ void convert_e0(const float* __restrict__ Eu,
                           const float* __restrict__ Ei,
                           unsigned short* __restrict__ Ecat,
                           long long nuD, long long nD) {
    long long stride = (long long)gridDim.x * blockDim.x * 4;
    for (long long i = ((long long)blockIdx.x * blockDim.x + threadIdx.x) * 4;
         i < nD; i += stride) {
        const float* src = (i < nuD) ? (Eu + i) : (Ei + (i - nuD));
        float4 f = *(const float4*)src;
        unsigned short o0 = f32_to_bf16(f.x), o1 = f32_to_bf16(f.y);
        unsigned short o2 = f32_to_bf16(f.z), o3 = f32_to_bf16(f.w);
        *(uint2*)(Ecat + i) =
            make_uint2(((unsigned)o1 << 16) | o0, ((unsigned)o3 << 16) | o2);
    }
}

// ---------------- accumulate (the SpMM) ----------------
// One block per coarse bucket, 8 waves; wave w owns rows [16w,16w+16),
// processed in pairs (A,B). Lane (q = lane>>4, m = lane&15): quarter q
// handles entries e0+q, e0+q+4, ...; lane gathers dims [4m,4m+4) as uint2.
// Row end: shfl_xor(16|32) reduce across quarters; q=0 lanes write row A,
// q=1 lanes write row B.
// FUSE=false: Zout_bf16[row] = sum           (layer 1)
// FUSE=true : out[row] = (E0 + Z1 + sum)/3   (layer 2 + combine)
template <bool FUSE>
__global__ __launch_bounds__(512, 8) void accum4_kernel(
    const int2* __restrict__ tmp, const int* __restrict__ bktBase,
    const int* __restrict__ rowBase,
    const unsigned short* __restrict__ gsrc,  // bf16 [nR][D] gather source
    const float* __restrict__ Eu0, const float* __restrict__ Ei0,
    const unsigned short* __restrict__ Z1,
    unsigned short* __restrict__ Zout,
    float* __restrict__ out,  // [nR][D] f32 (concatenated users+items)
    int nu, int nR) {
    int b = blockIdx.x;
    int w = threadIdx.x >> 6, lane = threadIdx.x & 63;
    int q = lane >> 4, m = lane & 15;
    int bEnd = bktBase[b + 1];
    const int* rb = rowBase + (size_t)b * RPB;
    int rb0 = rb[0];
    bool sorted = (rb0 >= 0);
    const uint2* gp = (const uint2*)gsrc + m;  // lane's dim slot (row stride 16)

    for (int k = 0; k < 16; k += 2) {
        int rlA = (w << 4) + k;
        int grA = b * RPB + rlA;
        if (grA >= nR) break;
        bool hasB = (grA + 1) < nR;

        float a0 = 0.f, a1 = 0.f, a2 = 0.f, a3 = 0.f;
        float b0 = 0.f, b1 = 0.f, b2 = 0.f, b3 = 0.f;

        if (sorted) {
            int eA0 = rb[rlA], eA1 = rb[rlA + 1];
            int eB0 = eA1;
            int eB1 = (rlA + 2 < RPB) ? rb[rlA + 2] : bEnd;
            if (!hasB) eB1 = eB0;
            int nA = eA1 - eA0, nB = eB1 - eB0;
            int iters = ((nA > nB ? nA : nB) + 3) >> 2;
            int eA = eA0 + q, eB = eB0 + q;
#pragma unroll 2
            for (int i = 0; i < iters; i++) {
                int2 sA = tmp[eA];
                int2 sB = tmp[eB];
                bool okA = eA < eA1, okB = eB < eB1;
                int rxA = okA ? (sA.x & 0x7FFFF) : 0;
                int rxB = okB ? (sB.x & 0x7FFFF) : 0;
                float vA = okA ? __int_as_float(sA.y) : 0.f;
                float vB = okB ? __int_as_float(sB.y) : 0.f;
                uint2 gA = gp[rxA << 4];
                uint2 gB = gp[rxB << 4];
                a0 += vA * bf16_lo(gA.x); a1 += vA * bf16_hi(gA.x);
                a2 += vA * bf16_lo(gA.y); a3 += vA * bf16_hi(gA.y);
                b0 += vB * bf16_lo(gB.x); b1 += vB * bf16_hi(gB.x);
                b2 += vB * bf16_lo(gB.y); b3 += vB * bf16_hi(gB.y);
                eA += 4; eB += 4;
            }
        } else {
            // unsorted oversized bucket (never expected): scan + filter
            int beg = -(rb0 + 1);
            int n = bEnd - beg;
            int iters = (n + 3) >> 2;
            int e = beg + q;
            for (int i = 0; i < iters; i++) {
                int2 s = tmp[e];
                int rl = (s.x >> 19) & (RPB - 1);
                bool in = e < bEnd;
                bool okA = in && (rl == rlA);
                bool okB = in && hasB && (rl == rlA + 1);
                int rx = (okA | okB) ? (s.x & 0x7FFFF) : 0;
                float vA = okA ? __int_as_float(s.y) : 0.f;
                float vB = okB ? __int_as_float(s.y) : 0.f;
                uint2 g = gp[rx << 4];
                a0 += vA * bf16_lo(g.x); a1 += vA * bf16_hi(g.x);
                a2 += vA * bf16_lo(g.y); a3 += vA * bf16_hi(g.y);
                b0 += vB * bf16_lo(g.x); b1 += vB * bf16_hi(g.x);
                b2 += vB * bf16_lo(g.y); b3 += vB * bf16_hi(g.y);
                e += 4;
            }
        }

        // reduce across quarters (xor 16, 32): all lanes end with full sums
        a0 += __shfl_xor(a0, 16, 64); a0 += __shfl_xor(a0, 32, 64);
        a1 += __shfl_xor(a1, 16, 64); a1 += __shfl_xor(a1, 32, 64);
        a2 += __shfl_xor(a2, 16, 64); a2 += __shfl_xor(a2, 32, 64);
        a3 += __shfl_xor(a3, 16, 64); a3 += __shfl_xor(a3, 32, 64);
        b0 += __shfl_xor(b0, 16, 64); b0 += __shfl_xor(b0, 32, 64);
        b1 += __shfl_xor(b1, 16, 64); b1 += __shfl_xor(b1, 32, 64);
        b2 += __shfl_xor(b2, 16, 64); b2 += __shfl_xor(b2, 32, 64);
        b3 += __shfl_xor(b3, 16, 64); b3 += __shfl_xor(b3, 32, 64);

        // q=0 lanes write row A; q=1 lanes write row B
        int wr = (q == 0) ? grA : ((q == 1 && hasB) ? grA + 1 : -1);
        if (wr >= 0) {
            float r0 = (q == 0) ? a0 : b0;
            float r1 = (q == 0) ? a1 : b1;
            float r2 = (q == 0) ? a2 : b2;
            float r3 = (q == 0) ? a3 : b3;
            long long o = (long long)wr * D + m * 4;
            if (!FUSE) {
                unsigned p0 = ((unsigned)f32_to_bf16(r1) << 16) | f32_to_bf16(r0);
                unsigned p1 = ((unsigned)f32_to_bf16(r3) << 16) | f32_to_bf16(r2);
                *(uint2*)(Zout + o) = make_uint2(p0, p1);
            } else {
                const float* e0p = (wr < nu)
                    ? (Eu0 + o) : (Ei0 + o - (long long)nu * D);
                float4 e0 = *(const float4*)e0p;
                uint2 z = *(const uint2*)(Z1 + o);
                const float inv3 = 1.f / 3.f;
                float4 ov;
                ov.x = (e0.x + bf16_lo(z.x) + r0) * inv3;
                ov.y = (e0.y + bf16_hi(z.x) + r1) * inv3;
                ov.z = (e0.z + bf16_lo(z.y) + r2) * inv3;
                ov.w = (e0.w + bf16_hi(z.y) + r3) * inv3;
                *(float4*)(out + o) = ov;
            }
        }
    }
}

// ---------------- fallback (atomic scatter, needs only 77 MB ws) ----------------

__global__ void spmm_edge(const float* __restrict__ vals,
                          const int* __restrict__ rows,
                          const int* __restrict__ cols,
                          const float* __restrict__ Eu,
                          const float* __restrict__ Ei,
                          float* __restrict__ Zu, float* __restrict__ Zi,
                          float scale, int nnz) {
    long long gid = (long long)blockIdx.x * blockDim.x + threadIdx.x;
    if (gid >= (long long)nnz * D) return;
    int e = (int)(gid >> 6);
    int d = (int)(gid & 63);
    float v = vals[e] * scale;
    long long r = rows[e];
    long long c = cols[e];
    atomicAdd(&Zu[r * D + d], v * Ei[c * D + d]);
    atomicAdd(&Zi[c * D + d], v * Eu[r * D + d]);
}

__global__ void combine_kernel(const float* __restrict__ E0,
                               const float* __restrict__ Z1,
                               float* __restrict__ out, long long n4) {
    long long i = (long long)blockIdx.x * blockDim.x + threadIdx.x;
    if (i >= n4) return;
    const float4 a = reinterpret_cast<const float4*>(E0)[i];
    const float4 b = reinterpret_cast<const float4*>(Z1)[i];
    const float inv3 = 1.0f / 3.0f;
    float4 o;
    o.x = (a.x + b.x) * inv3;
    o.y = (a.y + b.y) * inv3;
    o.z = (a.z + b.z) * inv3;
    o.w = (a.w + b.w) * inv3;
    reinterpret_cast<float4*>(out)[i] = o;
}

// ---------------- launcher ----------------

static inline size_t align256(size_t x) { return (x + 255) & ~(size_t)255; }

extern "C" void kernel_launch(void* const* d_in, const int* in_sizes, int n_in,
                              void* d_out, int out_size, void* d_ws, size_t ws_size,
                              hipStream_t stream) {
    const float* user_emb = (const float*)d_in[0];
    const float* item_emb = (const float*)d_in[1];
    const float* vals     = (const float*)d_in[2];
    const int*   rows     = (const int*)d_in[3];
    const int*   cols     = (const int*)d_in[4];

    const int nu  = in_sizes[0] / D;  // 100000
    const int ni  = in_sizes[1] / D;  // 200000
    const int nnz = in_sizes[2];      // 5000000
    const int nR  = nu + ni;
    const int NB  = (nR + RPB - 1) / RPB;  // 2344

    float* out = (float*)d_out;  // [nR][D], users then items

    // ws layout (tmp has +16 entries of slack for masked overshoot reads)
    size_t off = 0;
    size_t o_tmp  = off; off += align256(((size_t)2 * nnz + 16) * sizeof(int2));
    size_t o_E    = off; off += align256((size_t)nR * D * sizeof(unsigned short));
    size_t o_Z1   = off; off += align256((size_t)nR * D * sizeof(unsigned short));
    size_t o_cnt  = off; off += align256((size_t)(NB + 1) * sizeof(int));
    size_t o_base = off; off += align256((size_t)(NB + 2) * sizeof(int));
    size_t o_cur  = off; off += align256((size_t)(NB + 1) * sizeof(int));
    size_t o_row  = off; off += align256((size_t)NB * RPB * sizeof(int));
    size_t needed = off;

    bool fits19 = (nR < (1 << 19));  // src index must pack in 19 bits

    if (ws_size >= needed && NB <= NBMAX && fits19) {
        char* w = (char*)d_ws;
        int2*           tmp      = (int2*)(w + o_tmp);
        unsigned short* Ecat     = (unsigned short*)(w + o_E);
        unsigned short* Z1bf     = (unsigned short*)(w + o_Z1);
        int*            bktCnt   = (int*)(w + o_cnt);
        int*            bktBase  = (int*)(w + o_base);
        int*            bktCur   = (int*)(w + o_cur);
        int*            rowBase  = (int*)(w + o_row);

        hipMemsetAsync(bktCnt, 0, (size_t)NB * sizeof(int), stream);

        bucket_hist<<<512, 256, 0, stream>>>(rows, cols, bktCnt, nu, nnz, NB);
        scan_buckets<<<1, 256, 0, stream>>>(bktCnt, bktBase, bktCur, NB, 2 * nnz);

        unsigned gB = (unsigned)((nnz + PASSB_EDGES - 1) / PASSB_EDGES);
        pass_bucket<<<gB, 256, 0, stream>>>(vals, rows, cols, bktCur, tmp,
                                            nu, nnz, NB);
        refine_kernel<<<NB, 512, 0, stream>>>(tmp, bktBase, rowBase, NB);

        long long nD = (long long)nR * D;
        long long nuD = (long long)nu * D;
        unsigned gC = (unsigned)((nD / 4 + 255) / 256);
        if (gC > 4096) gC = 4096;
        convert_e0<<<gC, 256, 0, stream>>>(user_emb, item_emb, Ecat, nuD, nD);

        // Layer 1: Z1 = A_cat @ E0
        accum4_kernel<false><<<NB, 512, 0, stream>>>(
            tmp, bktBase, rowBase, Ecat, nullptr, nullptr, nullptr, Z1bf,
            nullptr, nu, nR);
        // Layer 2 + combine: out = (E0 + Z1 + A_cat @ Z1) / 3
        accum4_kernel<true><<<NB, 512, 0, stream>>>(
            tmp, bktBase, rowBase, Z1bf, user_emb, item_emb, Z1bf, nullptr,
            out, nu, nR);
    } else {
        // Fallback: atomic scatter, needs only (nu+ni)*D*4 bytes of ws.
        float* Zu1 = (float*)d_ws;
        float* Zi1 = Zu1 + (size_t)nu * D;
        float* out_u = out;
        float* out_i = out + (size_t)nu * D;
        hipMemsetAsync(d_ws, 0, (size_t)nR * D * sizeof(float), stream);

        const int threads = 256;
        long long tot = (long long)nnz * D;
        unsigned blocks = (unsigned)((tot + threads - 1) / threads);

        spmm_edge<<<blocks, threads, 0, stream>>>(vals, rows, cols, user_emb,
                                                  item_emb, Zu1, Zi1, 1.0f, nnz);
        long long nu4 = (long long)nu * D / 4;
        long long ni4 = (long long)ni * D / 4;
        combine_kernel<<<(unsigned)((nu4 + 255) / 256), 256, 0, stream>>>(
            user_emb, Zu1, out_u, nu4);
        combine_kernel<<<(unsigned)((ni4 + 255) / 256), 256, 0, stream>>>(
            item_emb, Zi1, out_i, ni4);
        spmm_edge<<<blocks, threads, 0, stream>>>(vals, rows, cols, Zu1, Zi1,
                                                  out_u, out_i, 1.0f / 3.0f, nnz);
    }
}

// Round 7
// 788.768 us; speedup vs baseline: 9.6318x; 1.0086x over previous
//
#include <hip/hip_runtime.h>

// LightGCL forward: 2 layers of bipartite SpMM + mean of layer embeddings.
// Pipeline: bucket 10M (dest,src,val) entries into 128-row coarse buckets
// (chunk-grouped dense writes, 1024-thr blocks), refine each bucket in-place
// sorted by ROW (128 bins, LDS-staged, 1024-thr), then accumulate with
// quarter-wave entry streams and a 2-deep software pipeline: tmp prefetched
// 2 iters ahead, gathers issued 1 iter ahead, ~8 loads in flight per wave.
// No atomics and no LDS in the hot loop.

constexpr int D = 64;
constexpr int RPB = 128;            // rows per coarse bucket
constexpr int NBMAX = 2560;         // LDS histogram capacity
constexpr int REF_CAP = 8000;       // refine LDS staging capacity (entries)
constexpr int PASSB_EDGES = 16384;  // edges per block in pass_bucket

static __device__ __forceinline__ unsigned short f32_to_bf16(float f) {
    unsigned u = __float_as_uint(f);
    unsigned r = u + 0x7FFFu + ((u >> 16) & 1u);
    return (unsigned short)(r >> 16);
}
static __device__ __forceinline__ float bf16_lo(unsigned g) {
    return __uint_as_float(g << 16);
}
static __device__ __forceinline__ float bf16_hi(unsigned g) {
    return __uint_as_float(g & 0xFFFF0000u);
}
static __device__ __forceinline__ float bf16_to_f32(unsigned short h) {
    return __uint_as_float(((unsigned)h) << 16);
}

// ---------------- bucket build ----------------

__global__ __launch_bounds__(1024) void bucket_hist(
    const int* __restrict__ rows, const int* __restrict__ cols,
    int* __restrict__ bktCnt, int nu, int nnz, int NB) {
    __shared__ int cnt[NBMAX];
    for (int i = threadIdx.x; i < NB; i += blockDim.x) cnt[i] = 0;
    __syncthreads();
    int stride = gridDim.x * blockDim.x;
    for (int e = blockIdx.x * blockDim.x + threadIdx.x; e < nnz; e += stride) {
        atomicAdd(&cnt[rows[e] >> 7], 1);
        atomicAdd(&cnt[(nu + cols[e]) >> 7], 1);
    }
    __syncthreads();
    for (int i = threadIdx.x; i < NB; i += blockDim.x)
        if (cnt[i]) atomicAdd(&bktCnt[i], cnt[i]);
}

// Exclusive scan of bucket counts (single block, NB <= NBMAX).
__global__ void scan_buckets(const int* __restrict__ bktCnt,
                             int* __restrict__ bktBase, int* __restrict__ bktCur,
                             int NB, int total) {
    __shared__ int tsum[256];
    int t = threadIdx.x;
    const int IT = (NB + 255) / 256;  // <= 10
    int v[10];
    int s = 0;
    for (int k = 0; k < IT; k++) {
        int i = t * IT + k;
        v[k] = (i < NB) ? bktCnt[i] : 0;
        s += v[k];
    }
    tsum[t] = s;
    __syncthreads();
    for (int off = 1; off < 256; off <<= 1) {
        int x = (t >= off) ? tsum[t - off] : 0;
        __syncthreads();
        tsum[t] += x;
        __syncthreads();
    }
    int excl = (t > 0) ? tsum[t - 1] : 0;
    for (int k = 0; k < IT; k++) {
        int i = t * IT + k;
        if (i < NB) { bktBase[i] = excl; bktCur[i] = excl; excl += v[k]; }
    }
    if (t == 255) bktBase[NB] = total;
}

// Scatter entries grouped by coarse bucket; per-block chunk reservation makes
// the global writes dense. Pack: x = (rowlocal<<19) | src_global, y = val bits.
// 1024 threads (16 waves) quarter the per-wave serial chain vs 256 threads.
__global__ __launch_bounds__(1024) void pass_bucket(
    const float* __restrict__ vals, const int* __restrict__ rows,
    const int* __restrict__ cols, int* __restrict__ bktCur,
    int2* __restrict__ tmp, int nu, int nnz, int NB) {
    __shared__ int cnt[NBMAX];
    for (int i = threadIdx.x; i < NB; i += 1024) cnt[i] = 0;
    __syncthreads();
    int base = blockIdx.x * PASSB_EDGES;
    for (int k = 0; k < PASSB_EDGES / 1024; k++) {
        int e = base + k * 1024 + threadIdx.x;
        if (e < nnz) {
            atomicAdd(&cnt[rows[e] >> 7], 1);
            atomicAdd(&cnt[(nu + cols[e]) >> 7], 1);
        }
    }
    __syncthreads();
    for (int i = threadIdx.x; i < NB; i += 1024) {
        int c = cnt[i];
        if (c) cnt[i] = atomicAdd(&bktCur[i], c);  // chunk base -> LDS cursor
    }
    __syncthreads();
    for (int k = 0; k < PASSB_EDGES / 1024; k++) {
        int e = base + k * 1024 + threadIdx.x;
        if (e < nnz) {
            int r = rows[e], c = cols[e];
            int iv = __float_as_int(vals[e]);
            int gi = nu + c;
            int p1 = atomicAdd(&cnt[r >> 7], 1);
            tmp[p1] = make_int2(((r & 127) << 19) | gi, iv);
            int p2 = atomicAdd(&cnt[gi >> 7], 1);
            tmp[p2] = make_int2(((gi & 127) << 19) | r, iv);
        }
    }
}

// Refine one coarse bucket in place: sort its entries by local row (128 bins)
// via LDS staging. rowBase[b*RPB + r] = start of row r's segment.
// Oversized buckets (> REF_CAP, +57 sigma, never for this input) keep a
// negative sentinel in rowBase[b*RPB] and are handled by a scan fallback.
__global__ __launch_bounds__(1024) void refine_kernel(
    int2* __restrict__ tmp, const int* __restrict__ bktBase,
    int* __restrict__ rowBase, int NB) {
    __shared__ int2 stage[REF_CAP];
    __shared__ int h[RPB], cur[RPB];
    int b = blockIdx.x;
    int beg = bktBase[b], end = bktBase[b + 1];
    int n = end - beg;
    int t = threadIdx.x;
    if (t < RPB) h[t] = 0;
    __syncthreads();
    if (n <= REF_CAP) {
        for (int e = t; e < n; e += 1024) {
            int2 v = tmp[beg + e];
            stage[e] = v;
            atomicAdd(&h[(v.x >> 19) & (RPB - 1)], 1);
        }
        __syncthreads();
        int myc = (t < RPB) ? h[t] : 0;
        // Hillis-Steele inclusive scan over 128 bins
        for (int off = 1; off < RPB; off <<= 1) {
            int x = 0;
            if (t < RPB && t >= off) x = h[t - off];
            __syncthreads();
            if (t < RPB) h[t] += x;
            __syncthreads();
        }
        if (t < RPB) {
            int excl = beg + h[t] - myc;
            cur[t] = excl;
            rowBase[(size_t)b * RPB + t] = excl;
        }
        __syncthreads();
        for (int e = t; e < n; e += 1024) {
            int2 v = stage[e];
            int p = atomicAdd(&cur[(v.x >> 19) & (RPB - 1)], 1);
            tmp[p] = v;
        }
    } else {
        if (t < RPB) rowBase[(size_t)b * RPB + t] = (t == 0) ? -(beg + 1) : 0;
    }
}

// Concat + convert f32 embeddings -> bf16 table [nR][D].
__global__ void convert_e0(const float* __restrict__ Eu,
                           const float* __restrict__ Ei,
                           unsigned short* __restrict__ Ecat,
                           long long nuD, long long nD) {
    long long stride = (long long)gridDim.x * blockDim.x * 4;
    for (long long i = ((long long)blockIdx.x * blockDim.x + threadIdx.x) * 4;
         i < nD; i += stride) {
        const float* src = (i < nuD) ? (Eu + i) : (Ei + (i - nuD));
        float4 f = *(const float4*)src;
        unsigned short o0 = f32_to_bf16(f.x), o1 = f32_to_bf16(f.y);
        unsigned short o2 = f32_to_bf16(f.z), o3 = f32_to_bf16(f.w);
        *(uint2*)(Ecat + i) =
            make_uint2(((unsigned)o1 << 16) | o0, ((unsigned)o3 << 16) | o2);
    }
}

// ---------------- accumulate (the SpMM) ----------------
// One block per coarse bucket, 8 waves; wave w owns rows [16w,16w+16),
// processed in pairs (A,B). Lane (q = lane>>4, m = lane&15): quarter q
// handles entries e0+q, e0+q+4, ...; lane gathers dims [4m,4m+4) as uint2.
// 2-deep software pipeline: tmp loads issued 2 iters ahead, gathers 1 iter
// ahead; FMAs consume last iter's gathers -> ~8 loads in flight per wave.
// Row end: shfl_xor(16|32) reduce across quarters; q=0 writes row A, q=1 B.
// FUSE=false: Zout_bf16[row] = sum           (layer 1)
// FUSE=true : out[row] = (E0 + Z1 + sum)/3   (layer 2 + combine)
template <bool FUSE>
__global__ __launch_bounds__(512, 6) void accum5_kernel(
    const int2* __restrict__ tmp, const int* __restrict__ bktBase,
    const int* __restrict__ rowBase,
    const unsigned short* __restrict__ gsrc,  // bf16 [nR][D] gather source
    const float* __restrict__ Eu0, const float* __restrict__ Ei0,
    const unsigned short* __restrict__ Z1,
    unsigned short* __restrict__ Zout,
    float* __restrict__ out,  // [nR][D] f32 (concatenated users+items)
    int nu, int nR) {
    int b = blockIdx.x;
    int w = threadIdx.x >> 6, lane = threadIdx.x & 63;
    int q = lane >> 4, m = lane & 15;
    int bEnd = bktBase[b + 1];
    const int* rb = rowBase + (size_t)b * RPB;
    int rb0 = rb[0];
    bool sorted = (rb0 >= 0);
    const uint2* gp = (const uint2*)gsrc + m;  // lane's dim slot (row stride 16)

    for (int k = 0; k < 16; k += 2) {
        int rlA = (w << 4) + k;
        int grA = b * RPB + rlA;
        if (grA >= nR) break;
        bool hasB = (grA + 1) < nR;

        float a0 = 0.f, a1 = 0.f, a2 = 0.f, a3 = 0.f;
        float b0 = 0.f, b1 = 0.f, b2 = 0.f, b3 = 0.f;

        if (sorted) {
            int eA0 = rb[rlA], eA1 = rb[rlA + 1];
            int eB0 = eA1;
            int eB1 = (rlA + 2 < RPB) ? rb[rlA + 2] : bEnd;
            if (!hasB) eB1 = eB0;
            int nA = eA1 - eA0, nB = eB1 - eB0;
            int iters = ((nA > nB ? nA : nB) + 3) >> 2;
            int eA = eA0 + q, eB = eB0 + q;

            // pipeline prologue: tmp for i=0,1; gather+val for i=0
            int2 sAc = tmp[eA], sBc = tmp[eB];
            int2 sAn = tmp[eA + 4], sBn = tmp[eB + 4];
            bool okA = eA < eA1, okB = eB < eB1;
            uint2 gAc = gp[(okA ? (sAc.x & 0x7FFFF) : 0) << 4];
            uint2 gBc = gp[(okB ? (sBc.x & 0x7FFFF) : 0) << 4];
            float vAc = okA ? __int_as_float(sAc.y) : 0.f;
            float vBc = okB ? __int_as_float(sBc.y) : 0.f;

            for (int i = 0; i < iters; i++) {
                int2 sAn2 = tmp[eA + 8];            // tmp for i+2
                int2 sBn2 = tmp[eB + 8];
                bool okA1 = (eA + 4) < eA1;          // gather for i+1
                bool okB1 = (eB + 4) < eB1;
                uint2 gAn = gp[(okA1 ? (sAn.x & 0x7FFFF) : 0) << 4];
                uint2 gBn = gp[(okB1 ? (sBn.x & 0x7FFFF) : 0) << 4];
                float vAn = okA1 ? __int_as_float(sAn.y) : 0.f;
                float vBn = okB1 ? __int_as_float(sBn.y) : 0.f;

                a0 += vAc * bf16_lo(gAc.x); a1 += vAc * bf16_hi(gAc.x);
                a2 += vAc * bf16_lo(gAc.y); a3 += vAc * bf16_hi(gAc.y);
                b0 += vBc * bf16_lo(gBc.x); b1 += vBc * bf16_hi(gBc.x);
                b2 += vBc * bf16_lo(gBc.y); b3 += vBc * bf16_hi(gBc.y);

                sAn = sAn2; sBn = sBn2;
                gAc = gAn;  gBc = gBn;
                vAc = vAn;  vBc = vBn;
                eA += 4; eB += 4;
            }
        } else {
            // unsorted oversized bucket (never expected): scan + filter
            int beg = -(rb0 + 1);
            int n = bEnd - beg;
            int iters = (n + 3) >> 2;
            int e = beg + q;
            for (int i = 0; i < iters; i++) {
                int2 s = tmp[e];
                int rl = (s.x >> 19) & (RPB - 1);
                bool in = e < bEnd;
                bool okA = in && (rl == rlA);
                bool okB = in && hasB && (rl == rlA + 1);
                int rx = (okA | okB) ? (s.x & 0x7FFFF) : 0;
                float vA = okA ? __int_as_float(s.y) : 0.f;
                float vB = okB ? __int_as_float(s.y) : 0.f;
                uint2 g = gp[rx << 4];
                a0 += vA * bf16_lo(g.x); a1 += vA * bf16_hi(g.x);
                a2 += vA * bf16_lo(g.y); a3 += vA * bf16_hi(g.y);
                b0 += vB * bf16_lo(g.x); b1 += vB * bf16_hi(g.x);
                b2 += vB * bf16_lo(g.y); b3 += vB * bf16_hi(g.y);
                e += 4;
            }
        }

        // reduce across quarters (xor 16, 32): all lanes end with full sums
        a0 += __shfl_xor(a0, 16, 64); a0 += __shfl_xor(a0, 32, 64);
        a1 += __shfl_xor(a1, 16, 64); a1 += __shfl_xor(a1, 32, 64);
        a2 += __shfl_xor(a2, 16, 64); a2 += __shfl_xor(a2, 32, 64);
        a3 += __shfl_xor(a3, 16, 64); a3 += __shfl_xor(a3, 32, 64);
        b0 += __shfl_xor(b0, 16, 64); b0 += __shfl_xor(b0, 32, 64);
        b1 += __shfl_xor(b1, 16, 64); b1 += __shfl_xor(b1, 32, 64);
        b2 += __shfl_xor(b2, 16, 64); b2 += __shfl_xor(b2, 32, 64);
        b3 += __shfl_xor(b3, 16, 64); b3 += __shfl_xor(b3, 32, 64);

        // q=0 lanes write row A; q=1 lanes write row B
        int wr = (q == 0) ? grA : ((q == 1 && hasB) ? grA + 1 : -1);
        if (wr >= 0) {
            float r0 = (q == 0) ? a0 : b0;
            float r1 = (q == 0) ? a1 : b1;
            float r2 = (q == 0) ? a2 : b2;
            float r3 = (q == 0) ? a3 : b3;
            long long o = (long long)wr * D + m * 4;
            if (!FUSE) {
                unsigned p0 = ((unsigned)f32_to_bf16(r1) << 16) | f32_to_bf16(r0);
                unsigned p1 = ((unsigned)f32_to_bf16(r3) << 16) | f32_to_bf16(r2);
                *(uint2*)(Zout + o) = make_uint2(p0, p1);
            } else {
                const float* e0p = (wr < nu)
                    ? (Eu0 + o) : (Ei0 + o - (long long)nu * D);
                float4 e0 = *(const float4*)e0p;
                uint2 z = *(const uint2*)(Z1 + o);
                const float inv3 = 1.f / 3.f;
                float4 ov;
                ov.x = (e0.x + bf16_lo(z.x) + r0) * inv3;
                ov.y = (e0.y + bf16_hi(z.x) + r1) * inv3;
                ov.z = (e0.z + bf16_lo(z.y) + r2) * inv3;
                ov.w = (e0.w + bf16_hi(z.y) + r3) * inv3;
                *(float4*)(out + o) = ov;
            }
        }
    }
}

// ---------------- fallback (atomic scatter, needs only 77 MB ws) ----------------

__global__ void spmm_edge(const float* __restrict__ vals,
                          const int* __restrict__ rows,
                          const int* __restrict__ cols,
                          const float* __restrict__ Eu,
                          const float* __restrict__ Ei,
                          float* __restrict__ Zu, float* __restrict__ Zi,
                          float scale, int nnz) {
    long long gid = (long long)blockIdx.x * blockDim.x + threadIdx.x;
    if (gid >= (long long)nnz * D) return;
    int e = (int)(gid >> 6);
    int d = (int)(gid & 63);
    float v = vals[e] * scale;
    long long r = rows[e];
    long long c = cols[e];
    atomicAdd(&Zu[r * D + d], v * Ei[c * D + d]);
    atomicAdd(&Zi[c * D + d], v * Eu[r * D + d]);
}

__global__ void combine_kernel(const float* __restrict__ E0,
                               const float* __restrict__ Z1,
                               float* __restrict__ out, long long n4) {
    long long i = (long long)blockIdx.x * blockDim.x + threadIdx.x;
    if (i >= n4) return;
    const float4 a = reinterpret_cast<const float4*>(E0)[i];
    const float4 b = reinterpret_cast<const float4*>(Z1)[i];
    const float inv3 = 1.0f / 3.0f;
    float4 o;
    o.x = (a.x + b.x) * inv3;
    o.y = (a.y + b.y) * inv3;
    o.z = (a.z + b.z) * inv3;
    o.w = (a.w + b.w) * inv3;
    reinterpret_cast<float4*>(out)[i] = o;
}

// ---------------- launcher ----------------

static inline size_t align256(size_t x) { return (x + 255) & ~(size_t)255; }

extern "C" void kernel_launch(void* const* d_in, const int* in_sizes, int n_in,
                              void* d_out, int out_size, void* d_ws, size_t ws_size,
                              hipStream_t stream) {
    const float* user_emb = (const float*)d_in[0];
    const float* item_emb = (const float*)d_in[1];
    const float* vals     = (const float*)d_in[2];
    const int*   rows     = (const int*)d_in[3];
    const int*   cols     = (const int*)d_in[4];

    const int nu  = in_sizes[0] / D;  // 100000
    const int ni  = in_sizes[1] / D;  // 200000
    const int nnz = in_sizes[2];      // 5000000
    const int nR  = nu + ni;
    const int NB  = (nR + RPB - 1) / RPB;  // 2344

    float* out = (float*)d_out;  // [nR][D], users then items

    // ws layout (tmp has +16 entries of slack for pipelined overshoot reads)
    size_t off = 0;
    size_t o_tmp  = off; off += align256(((size_t)2 * nnz + 16) * sizeof(int2));
    size_t o_E    = off; off += align256((size_t)nR * D * sizeof(unsigned short));
    size_t o_Z1   = off; off += align256((size_t)nR * D * sizeof(unsigned short));
    size_t o_cnt  = off; off += align256((size_t)(NB + 1) * sizeof(int));
    size_t o_base = off; off += align256((size_t)(NB + 2) * sizeof(int));
    size_t o_cur  = off; off += align256((size_t)(NB + 1) * sizeof(int));
    size_t o_row  = off; off += align256((size_t)NB * RPB * sizeof(int));
    size_t needed = off;

    bool fits19 = (nR < (1 << 19));  // src index must pack in 19 bits

    if (ws_size >= needed && NB <= NBMAX && fits19) {
        char* w = (char*)d_ws;
        int2*           tmp      = (int2*)(w + o_tmp);
        unsigned short* Ecat     = (unsigned short*)(w + o_E);
        unsigned short* Z1bf     = (unsigned short*)(w + o_Z1);
        int*            bktCnt   = (int*)(w + o_cnt);
        int*            bktBase  = (int*)(w + o_base);
        int*            bktCur   = (int*)(w + o_cur);
        int*            rowBase  = (int*)(w + o_row);

        hipMemsetAsync(bktCnt, 0, (size_t)NB * sizeof(int), stream);

        bucket_hist<<<512, 1024, 0, stream>>>(rows, cols, bktCnt, nu, nnz, NB);
        scan_buckets<<<1, 256, 0, stream>>>(bktCnt, bktBase, bktCur, NB, 2 * nnz);

        unsigned gB = (unsigned)((nnz + PASSB_EDGES - 1) / PASSB_EDGES);
        pass_bucket<<<gB, 1024, 0, stream>>>(vals, rows, cols, bktCur, tmp,
                                             nu, nnz, NB);
        refine_kernel<<<NB, 1024, 0, stream>>>(tmp, bktBase, rowBase, NB);

        long long nD = (long long)nR * D;
        long long nuD = (long long)nu * D;
        unsigned gC = (unsigned)((nD / 4 + 255) / 256);
        if (gC > 4096) gC = 4096;
        convert_e0<<<gC, 256, 0, stream>>>(user_emb, item_emb, Ecat, nuD, nD);

        // Layer 1: Z1 = A_cat @ E0
        accum5_kernel<false><<<NB, 512, 0, stream>>>(
            tmp, bktBase, rowBase, Ecat, nullptr, nullptr, nullptr, Z1bf,
            nullptr, nu, nR);
        // Layer 2 + combine: out = (E0 + Z1 + A_cat @ Z1) / 3
        accum5_kernel<true><<<NB, 512, 0, stream>>>(
            tmp, bktBase, rowBase, Z1bf, user_emb, item_emb, Z1bf, nullptr,
            out, nu, nR);
    } else {
        // Fallback: atomic scatter, needs only (nu+ni)*D*4 bytes of ws.
        float* Zu1 = (float*)d_ws;
        float* Zi1 = Zu1 + (size_t)nu * D;
        float* out_u = out;
        float* out_i = out + (size_t)nu * D;
        hipMemsetAsync(d_ws, 0, (size_t)nR * D * sizeof(float), stream);

        const int threads = 256;
        long long tot = (long long)nnz * D;
        unsigned blocks = (unsigned)((tot + threads - 1) / threads);

        spmm_edge<<<blocks, threads, 0, stream>>>(vals, rows, cols, user_emb,
                                                  item_emb, Zu1, Zi1, 1.0f, nnz);
        long long nu4 = (long long)nu * D / 4;
        long long ni4 = (long long)ni * D / 4;
        combine_kernel<<<(unsigned)((nu4 + 255) / 256), 256, 0, stream>>>(
            user_emb, Zu1, out_u, nu4);
        combine_kernel<<<(unsigned)((ni4 + 255) / 256), 256, 0, stream>>>(
            item_emb, Zi1, out_i, ni4);
        spmm_edge<<<blocks, threads, 0, stream>>>(vals, rows, cols, Zu1, Zi1,
                                                  out_u, out_i, 1.0f / 3.0f, nnz);
    }
}